// Round 4
// baseline (344.662 us; speedup 1.0000x reference)
//
#include <hip/hip_runtime.h>

// SelfAttention: x(8,2048,768) fp32, W_q/W_k/W_v (768,768) fp32 -> H fp32.
// Algebraic rewrite: S = x (Wq^T Wk / sqrt(D)) x^T:
//   prep(cvt x,Wv + transpose Wq,Wk) ; G2 = NT(WkT,WqT)*scale ;
//   {T~ = NT(x,G2) ; Vt = (x@Wv^T)^T} fused dual dispatch ;
//   P' = exp(NT(T~,x)) + rowsums ; H = NT(P',Vt)/rowsum
// GEMM core = R0's proven structure: 128x128 block, 4 waves of 64x64,
// 16x16x32 f16 MFMA, BK=64, two barriers/iter, chunk^(row&7) LDS swizzle,
// global_load_lds(16B) staging, LDS-staged coalesced epilogues, 4 blocks/CU.
// R4: dispatch fusion (7->5 launches) + bijective XCD-aware block swizzle (T1).

typedef _Float16 f16;
typedef __attribute__((ext_vector_type(4))) _Float16 f16x4;
typedef __attribute__((ext_vector_type(8))) _Float16 f16x8;
typedef __attribute__((ext_vector_type(4))) float    f32x4;

#define BM 128
#define BN 128
#define BKH 64                      // K-tile in halfs (128 B rows)

#define SEQ   2048
#define DIM   768
#define NBAT  8
#define MTOT  (NBAT * SEQ)          // 16384
#define XN    ((long)MTOT * DIM)    // 12582912
#define WN    (DIM * DIM)           // 589824
#define SB    ((long)SEQ * SEQ)
#define QB    ((long)SEQ * DIM)
#define XN4   3145728               // XN/4
#define WN4   147456                // WN/4
#define CVTB  12864                 // (XN4+WN4)/256

__device__ __forceinline__ void async_cp16(const void* g, void* l) {
  __builtin_amdgcn_global_load_lds((__attribute__((address_space(1))) void*)g,
                                   (__attribute__((address_space(3))) void*)l,
                                   16, 0, 0);
}

// Fused: fp32->f16 cvt of x,Wv (blocks 0..CVTB-1) + Wq/Wk transpose-cvt.
__global__ void prep(const float* __restrict__ x, const float* __restrict__ wv,
                     const float* __restrict__ wq, const float* __restrict__ wk,
                     f16* __restrict__ x16, f16* __restrict__ wv16,
                     f16* __restrict__ wqt, f16* __restrict__ wkt) {
  __shared__ float t[32][33];
  const int bid = blockIdx.x;
  if (bid < CVTB) {
    int i = bid * 256 + threadIdx.x;      // float4 index
    const float* src; f16* dst; int idx;
    if (i < XN4) { src = x; dst = x16; idx = i; }
    else { src = wv; dst = wv16; idx = i - XN4; }
    float4 v = ((const float4*)src)[idx];
    f16x4 o = {(f16)v.x, (f16)v.y, (f16)v.z, (f16)v.w};
    ((f16x4*)dst)[idx] = o;
  } else {
    const int b2 = bid - CVTB;            // 0..1151
    const int tz = b2 / 576, rr = b2 % 576;
    const float* src = tz ? wk : wq;
    f16* dst = tz ? wkt : wqt;
    const int bx = (rr % 24) * 32, by = (rr / 24) * 32;
    const int tx = threadIdx.x & 31, ty = threadIdx.x >> 5;   // 32 x 8
#pragma unroll
    for (int r = 0; r < 4; ++r)
      t[ty + 8 * r][tx] = src[(long)(by + ty + 8 * r) * DIM + bx + tx];
    __syncthreads();
#pragma unroll
    for (int r = 0; r < 4; ++r)
      dst[(long)(bx + ty + 8 * r) * DIM + by + tx] = (f16)t[tx][ty + 8 * r];
  }
}

// NT GEMM core: C[m][n] = sum_k A[m][k]*B[n][k].  128x128 block, 4 waves of 64x64.
// MODE 0: f16 row-major out; z==0 scaled by `scale` (used for G2 and T~).
// MODE 1: f16 out = exp(acc); rowsum partials -> Rsum[z][32][2048].
// MODE 2: fp32 out = acc * (1/rowsum) from Rsum partials.
// MODE 3: f16 transposed out Vt[b][n][m-local]. SWAP=false.
// SWAP=true: mfma(bf,af): lane&15 = m, regs = 4 consecutive n.
template <int MODE, bool SWAP>
__device__ __forceinline__
void gemm_core(const f16* __restrict__ Abase, long sAz,
               const f16* __restrict__ Bbase, long sBz,
               void* __restrict__ Cbase, long sCz,
               float* __restrict__ Rsum,
               int N, int K, float scale,
               int bxi, int byi, int z,
               char* smem, float* sinv)
{
  f16* lA = (f16*)smem;                        // [128][64] halfs
  f16* lB = (f16*)(smem + 16384);              // [128][64] halfs

  const int tid  = threadIdx.x;
  const int m0   = bxi * BM;
  const int n0   = byi * BN;
  const int wave = tid >> 6;
  const int lane = tid & 63;
  const int wm   = (wave & 1) * 64;
  const int wn   = (wave >> 1) * 64;

  const f16* A = Abase + (long)z * sAz;
  const f16* B = Bbase + (long)z * sBz;

  f32x4 acc[4][4] = {};

  if constexpr (MODE == 2) {
    if (tid < 128) {
      const float* rp = Rsum + (long)z * 32 * SEQ + m0 + tid;
      float s = 0.f;
#pragma unroll
      for (int k = 0; k < 32; ++k) s += rp[k * SEQ];
      sinv[tid] = 1.0f / s;
    }
    // ordered before epilogue reads by the in-loop barriers
  }

  // staging: thread t loads 16B: row srow (of 32-row group p), swizzled k-chunk.
  const int srow = tid >> 3;                         // 0..31
  const int gcol = ((tid & 7) ^ (srow & 7)) * 8;     // swizzle chunk by row&7
  const f16* ga = A + (long)(m0 + srow) * K + gcol;
  const f16* gb = B + (long)(n0 + srow) * K + gcol;
  f16* la = lA + tid * 8;
  f16* lb = lB + tid * 8;

  // MFMA fragment addressing: row = lane&15 (+16i +wm), k-chunk (s*4+q)^swz
  const int frow = lane & 15;
  const int q    = lane >> 4;
  const int swz  = frow & 7;
  const int aro  = (wm + frow) * BKH;
  const int bro  = (wn + frow) * BKH;

  for (int k0 = 0; k0 < K; k0 += BKH) {
#pragma unroll
    for (int p = 0; p < 4; ++p) {
      async_cp16(ga + (long)(p * 32) * K + k0, la + p * 2048);
      async_cp16(gb + (long)(p * 32) * K + k0, lb + p * 2048);
    }
    __syncthreads();
#pragma unroll
    for (int s = 0; s < 2; ++s) {
      const int co = ((s * 4 + q) ^ swz) * 8;
      f16x8 af[4], bf[4];
#pragma unroll
      for (int i = 0; i < 4; ++i) af[i] = *(const f16x8*)&lA[aro + i * 1024 + co];
#pragma unroll
      for (int j = 0; j < 4; ++j) bf[j] = *(const f16x8*)&lB[bro + j * 1024 + co];
#pragma unroll
      for (int i = 0; i < 4; ++i)
#pragma unroll
        for (int j = 0; j < 4; ++j)
          acc[i][j] = SWAP
            ? __builtin_amdgcn_mfma_f32_16x16x32_f16(bf[j], af[i], acc[i][j], 0, 0, 0)
            : __builtin_amdgcn_mfma_f32_16x16x32_f16(af[i], bf[j], acc[i][j], 0, 0, 0);
    }
    __syncthreads();   // frag reads done before next stage overwrites
  }

  const int TS = 136;  // f16 epilogue tile stride (halfs)

  if constexpr (MODE == 0 || MODE == 1) {
    f16* T = (f16*)smem;   // [128][TS]
    float rs[4] = {0.f, 0.f, 0.f, 0.f};
    const float sc = (MODE == 0 && z == 0) ? scale : 1.0f;
#pragma unroll
    for (int i = 0; i < 4; ++i)
#pragma unroll
      for (int j = 0; j < 4; ++j) {
        f16x4 v;
#pragma unroll
        for (int r = 0; r < 4; ++r) {
          float xv = acc[i][j][r];
          if (MODE == 1) xv = __expf(xv); else xv *= sc;
          v[r] = (f16)xv;
          if (MODE == 1) rs[i] += (float)v[r];   // sum of f16-rounded values
        }
        *(f16x4*)&T[(wm + i * 16 + frow) * TS + wn + j * 16 + q * 4] = v;
      }
    if constexpr (MODE == 1) {
#pragma unroll
      for (int i = 0; i < 4; ++i) {
        rs[i] += __shfl_xor(rs[i], 16);
        rs[i] += __shfl_xor(rs[i], 32);   // full 64-col segment sum
      }
      if (lane < 16) {   // q==0 lanes hold the reduced sums
        float* rp = Rsum + ((long)z * 32 + byi * 2 + (wn >> 6)) * SEQ + m0 + wm;
#pragma unroll
        for (int i = 0; i < 4; ++i) rp[i * 16 + frow] = rs[i];
      }
    }
    __syncthreads();
    f16* C = (f16*)Cbase + (long)z * sCz;
    const int row = tid >> 1, seg = (tid & 1) * 64;
#pragma unroll
    for (int k = 0; k < 8; ++k) {
      f16x8 v = *(const f16x8*)&T[row * TS + seg + k * 8];
      *(f16x8*)&C[(long)(m0 + row) * N + n0 + seg + k * 8] = v;
    }
  }

  if constexpr (MODE == 3) {   // Vt[b][d][s]; SWAP=false: regs = consecutive m (=s)
    f16* T = (f16*)smem;       // [n(=d) 128][TS] holding m(=s) contiguous
#pragma unroll
    for (int i = 0; i < 4; ++i)
#pragma unroll
      for (int j = 0; j < 4; ++j) {
        f16x4 v = {(f16)acc[i][j][0], (f16)acc[i][j][1],
                   (f16)acc[i][j][2], (f16)acc[i][j][3]};
        *(f16x4*)&T[(wn + j * 16 + frow) * TS + wm + i * 16 + q * 4] = v;
      }
    __syncthreads();
    f16* C = (f16*)Cbase;
    const int b = m0 >> 11, sl = m0 & 2047;
    const int row = tid >> 1, seg = (tid & 1) * 64;
#pragma unroll
    for (int k = 0; k < 8; ++k) {
      f16x8 v = *(const f16x8*)&T[row * TS + seg + k * 8];
      *(f16x8*)&C[(long)b * QB + (long)(n0 + row) * SEQ + sl + seg + k * 8] = v;
    }
  }

  if constexpr (MODE == 2) {   // fp32 out, normalized; 2-pass (64 rows) epilogue
    float inv[4];
#pragma unroll
    for (int i = 0; i < 4; ++i) inv[i] = sinv[wm + i * 16 + frow];

    float* Tf = (float*)smem;   // [64][FS] fp32
    const int FS = 132;
    float* C = (float*)Cbase + (long)z * sCz;
    for (int pass = 0; pass < 2; ++pass) {
      if (wm == pass * 64) {
#pragma unroll
        for (int i = 0; i < 4; ++i)
#pragma unroll
          for (int j = 0; j < 4; ++j) {
            f32x4 v = acc[i][j] * inv[i];
            *(f32x4*)&Tf[(i * 16 + frow) * FS + wn + j * 16 + q * 4] = v;
          }
      }
      __syncthreads();
      const int row = tid >> 2, cs = (tid & 3) * 32;
#pragma unroll
      for (int k = 0; k < 8; ++k) {
        f32x4 v = *(const f32x4*)&Tf[row * FS + cs + k * 4];
        *(f32x4*)&C[(long)(m0 + pass * 64 + row) * N + n0 + cs + k * 4] = v;
      }
      if (pass == 0) __syncthreads();
    }
  }
}

// Wrapper with optional bijective XCD-aware swizzle (grid count must be %8==0 when SWZ).
template <int MODE, bool SWAP, int SWZ>
__global__ __launch_bounds__(256, 4)
void gemm_nt(const f16* __restrict__ Abase, long sAz,
             const f16* __restrict__ Bbase, long sBz,
             void* __restrict__ Cbase, long sCz,
             float* __restrict__ Rsum,
             int N, int K, float scale)
{
  __shared__ __align__(16) char smem[34816];
  __shared__ float sinv[128];
  int bx = blockIdx.x, by = blockIdx.y, bz = blockIdx.z;
  if constexpr (SWZ) {
    const int nx = gridDim.x, ny = gridDim.y;
    const long nwg = (long)nx * ny * gridDim.z;
    const long id  = ((long)bz * ny + by) * nx + bx;
    const long cpx = nwg >> 3;                   // nwg % 8 == 0 at all call sites
    const long sid = (id & 7) * cpx + (id >> 3);
    bx = (int)(sid % nx);
    const long r2 = sid / nx;
    by = (int)(r2 % ny);
    bz = (int)(r2 / ny);
  }
  gemm_core<MODE, SWAP>(Abase, sAz, Bbase, sBz, Cbase, sCz, Rsum,
                        N, K, scale, bx, by, bz, smem, sinv);
}

// Fused dual dispatch: z-half 0 -> T~ = NT(x,G2) (MODE0), z-half 1 -> Vt (MODE3).
__global__ __launch_bounds__(256, 4)
void gemm_dual(const f16* __restrict__ x16, const f16* __restrict__ G2,
               const f16* __restrict__ Wv16,
               f16* __restrict__ T16, f16* __restrict__ Vt16)
{
  __shared__ __align__(16) char smem[34816];
  __shared__ float sinv[128];
  const int nx = 128, ny = 6;
  const long nwg = (long)nx * ny * 2;            // 1536, %8==0
  const long id  = ((long)blockIdx.z * ny + blockIdx.y) * nx + blockIdx.x;
  const long cpx = nwg >> 3;
  const long sid = (id & 7) * cpx + (id >> 3);
  const int bx = (int)(sid % nx);
  const long r2 = sid / nx;
  const int by = (int)(r2 % ny);
  const int bz = (int)(r2 / ny);
  if (bz == 0)
    gemm_core<0, true >(x16, 0L, G2,   0L, (void*)T16,  0L, nullptr,
                        DIM, DIM, 1.0f, bx, by, 0, smem, sinv);
  else
    gemm_core<3, false>(x16, 0L, Wv16, 0L, (void*)Vt16, 0L, nullptr,
                        DIM, DIM, 1.0f, bx, by, 0, smem, sinv);
}

extern "C" void kernel_launch(void* const* d_in, const int* in_sizes, int n_in,
                              void* d_out, int out_size, void* d_ws, size_t ws_size,
                              hipStream_t stream) {
  const float* x  = (const float*)d_in[0];
  const float* Wq = (const float*)d_in[1];
  const float* Wk = (const float*)d_in[2];
  const float* Wv = (const float*)d_in[3];

  f16* ws    = (f16*)d_ws;
  f16* x16   = ws;                  // XN
  f16* Wv16  = x16 + XN;            // WN
  f16* WqT16 = Wv16 + WN;           // WN
  f16* WkT16 = WqT16 + WN;          // WN
  f16* G2    = WkT16 + WN;          // WN   G2[e][d] = sum_k Wk[k][e]Wq[k][d] * scale
  f16* T16   = G2 + WN;             // XN   T~ = x @ G2^T
  f16* Vt16  = T16 + XN;            // XN   [b][d][s]
  f16* S16   = Vt16 + XN;           // NBAT*SB (exp scores, unnormalized)
  float* rsumP = (float*)(S16 + (long)NBAT * SB);   // [8][32][2048] partials

  // D1: cvt(x,Wv) + transpose(Wq,Wk), fused
  prep<<<CVTB + 1152, 256, 0, stream>>>(x, Wv, Wq, Wk, x16, Wv16, WqT16, WkT16);
  // D2: G2 = NT(WkT, WqT) * 1/sqrt(768)  (768x768x768; 36 blocks, unswizzled)
  gemm_nt<0, true, 0><<<dim3(6, 6, 1), 256, 0, stream>>>(
      WkT16, 0L, WqT16, 0L, (void*)G2, 0L, nullptr, DIM, DIM, 0.03608439182435161f);
  // D3: T~ = NT(x16, G2) and Vt = (x @ Wv^T)^T, fused dual (16384x768x768 each)
  gemm_dual<<<dim3(128, 6, 2), 256, 0, stream>>>(x16, G2, Wv16, T16, Vt16);
  // D4: P' = exp(T~ x^T) per batch + rowsum partials  (2048x2048x768 x8)
  gemm_nt<1, true, 1><<<dim3(SEQ / BM, SEQ / BN, NBAT), 256, 0, stream>>>(
      T16, QB, x16, QB, (void*)S16, SB, rsumP, SEQ, DIM, 1.0f);
  // D5: H = (P' @ Vt^T) / rowsum, fp32  (2048x768x2048 x8)
  gemm_nt<2, true, 1><<<dim3(SEQ / BM, DIM / BN, NBAT), 256, 0, stream>>>(
      S16, SB, Vt16, QB, d_out, QB, rsumP, DIM, SEQ, 1.0f);
}

// Round 5
// 313.881 us; speedup vs baseline: 1.0981x; 1.0981x over previous
//
#include <hip/hip_runtime.h>

// SelfAttention: x(8,2048,768) fp32, W_q/W_k/W_v (768,768) fp32 -> H fp32.
// Algebraic rewrite: S = x (Wq^T Wk / sqrt(D)) x^T:
//   prep(cvt x,Wv + transpose Wq,Wk) ; G2 = NT(WkT,WqT)*scale ;
//   T~ = NT(x,G2) ; Vt = (x@Wv^T)^T ; P' = exp(NT(T~,x)) + rowsums ;
//   H = NT(P',Vt)/rowsum
// R5 composition (no swizzle anywhere — default block->XCD map already
// co-locates same-bx blocks: id%8 == bx%8 when gridDim.x%8==0):
//   - prep: fused cvt+transpose (R4, measured OK)
//   - G2/T~/Vt: R0-proven 128x128 core, 4 blocks/CU (29 us each measured)
//   - P'/H (MODE1/MODE2): R2-measured 256x256 8-phase core (75/74 us)

typedef _Float16 f16;
typedef __attribute__((ext_vector_type(4))) _Float16 f16x4;
typedef __attribute__((ext_vector_type(8))) _Float16 f16x8;
typedef __attribute__((ext_vector_type(4))) float    f32x4;

#define BM 128
#define BN 128
#define BKH 64

#define SEQ   2048
#define DIM   768
#define NBAT  8
#define MTOT  (NBAT * SEQ)          // 16384
#define XN    ((long)MTOT * DIM)    // 12582912
#define WN    (DIM * DIM)           // 589824
#define SB    ((long)SEQ * SEQ)
#define QB    ((long)SEQ * DIM)
#define XN4   3145728               // XN/4
#define WN4   147456                // WN/4
#define CVTB  12864                 // (XN4+WN4)/256

__device__ __forceinline__ void async_cp16(const void* g, void* l) {
  __builtin_amdgcn_global_load_lds((__attribute__((address_space(1))) void*)g,
                                   (__attribute__((address_space(3))) void*)l,
                                   16, 0, 0);
}

// Fused: fp32->f16 cvt of x,Wv (blocks 0..CVTB-1) + Wq/Wk transpose-cvt.
__global__ void prep(const float* __restrict__ x, const float* __restrict__ wv,
                     const float* __restrict__ wq, const float* __restrict__ wk,
                     f16* __restrict__ x16, f16* __restrict__ wv16,
                     f16* __restrict__ wqt, f16* __restrict__ wkt) {
  __shared__ float t[32][33];
  const int bid = blockIdx.x;
  if (bid < CVTB) {
    int i = bid * 256 + threadIdx.x;      // float4 index
    const float* src; f16* dst; int idx;
    if (i < XN4) { src = x; dst = x16; idx = i; }
    else { src = wv; dst = wv16; idx = i - XN4; }
    float4 v = ((const float4*)src)[idx];
    f16x4 o = {(f16)v.x, (f16)v.y, (f16)v.z, (f16)v.w};
    ((f16x4*)dst)[idx] = o;
  } else {
    const int b2 = bid - CVTB;            // 0..1151
    const int tz = b2 / 576, rr = b2 % 576;
    const float* src = tz ? wk : wq;
    f16* dst = tz ? wkt : wqt;
    const int bx = (rr % 24) * 32, by = (rr / 24) * 32;
    const int tx = threadIdx.x & 31, ty = threadIdx.x >> 5;   // 32 x 8
#pragma unroll
    for (int r = 0; r < 4; ++r)
      t[ty + 8 * r][tx] = src[(long)(by + ty + 8 * r) * DIM + bx + tx];
    __syncthreads();
#pragma unroll
    for (int r = 0; r < 4; ++r)
      dst[(long)(bx + ty + 8 * r) * DIM + by + tx] = (f16)t[tx][ty + 8 * r];
  }
}

// ---------------- 128x128 NT GEMM (R0 structure) ----------------
// MODE 0: f16 row-major out; z==0 scaled by `scale`.  MODE 3: f16 transposed Vt.
template <int MODE, bool SWAP>
__global__ __launch_bounds__(256, 4)
void gemm128(const f16* __restrict__ Abase, long sAz,
             const f16* __restrict__ Bbase, long sBz,
             void* __restrict__ Cbase, long sCz,
             int N, int K, float scale)
{
  __shared__ __align__(16) char smem[34816];
  f16* lA = (f16*)smem;                        // [128][64] halfs
  f16* lB = (f16*)(smem + 16384);              // [128][64] halfs

  const int tid  = threadIdx.x;
  const int z    = blockIdx.z;
  const int m0   = blockIdx.x * BM;
  const int n0   = blockIdx.y * BN;
  const int wave = tid >> 6;
  const int lane = tid & 63;
  const int wm   = (wave & 1) * 64;
  const int wn   = (wave >> 1) * 64;

  const f16* A = Abase + (long)z * sAz;
  const f16* B = Bbase + (long)z * sBz;

  f32x4 acc[4][4] = {};

  const int srow = tid >> 3;                         // 0..31
  const int gcol = ((tid & 7) ^ (srow & 7)) * 8;     // swizzle chunk by row&7
  const f16* ga = A + (long)(m0 + srow) * K + gcol;
  const f16* gb = B + (long)(n0 + srow) * K + gcol;
  f16* la = lA + tid * 8;
  f16* lb = lB + tid * 8;

  const int frow = lane & 15;
  const int q    = lane >> 4;
  const int swz  = frow & 7;
  const int aro  = (wm + frow) * BKH;
  const int bro  = (wn + frow) * BKH;

  for (int k0 = 0; k0 < K; k0 += BKH) {
#pragma unroll
    for (int p = 0; p < 4; ++p) {
      async_cp16(ga + (long)(p * 32) * K + k0, la + p * 2048);
      async_cp16(gb + (long)(p * 32) * K + k0, lb + p * 2048);
    }
    __syncthreads();
#pragma unroll
    for (int s = 0; s < 2; ++s) {
      const int co = ((s * 4 + q) ^ swz) * 8;
      f16x8 af[4], bf[4];
#pragma unroll
      for (int i = 0; i < 4; ++i) af[i] = *(const f16x8*)&lA[aro + i * 1024 + co];
#pragma unroll
      for (int j = 0; j < 4; ++j) bf[j] = *(const f16x8*)&lB[bro + j * 1024 + co];
#pragma unroll
      for (int i = 0; i < 4; ++i)
#pragma unroll
        for (int j = 0; j < 4; ++j)
          acc[i][j] = SWAP
            ? __builtin_amdgcn_mfma_f32_16x16x32_f16(bf[j], af[i], acc[i][j], 0, 0, 0)
            : __builtin_amdgcn_mfma_f32_16x16x32_f16(af[i], bf[j], acc[i][j], 0, 0, 0);
    }
    __syncthreads();
  }

  const int TS = 136;

  if constexpr (MODE == 0) {
    f16* T = (f16*)smem;   // [128][TS]
    const float sc = (z == 0) ? scale : 1.0f;
#pragma unroll
    for (int i = 0; i < 4; ++i)
#pragma unroll
      for (int j = 0; j < 4; ++j) {
        f16x4 v;
#pragma unroll
        for (int r = 0; r < 4; ++r) v[r] = (f16)(acc[i][j][r] * sc);
        *(f16x4*)&T[(wm + i * 16 + frow) * TS + wn + j * 16 + q * 4] = v;
      }
    __syncthreads();
    f16* C = (f16*)Cbase + (long)z * sCz;
    const int row = tid >> 1, seg = (tid & 1) * 64;
#pragma unroll
    for (int k = 0; k < 8; ++k) {
      f16x8 v = *(const f16x8*)&T[row * TS + seg + k * 8];
      *(f16x8*)&C[(long)(m0 + row) * N + n0 + seg + k * 8] = v;
    }
  }

  if constexpr (MODE == 3) {   // Vt[b][d][s]; SWAP=false: regs = consecutive m (=s)
    f16* T = (f16*)smem;       // [n(=d) 128][TS] holding m(=s) contiguous
#pragma unroll
    for (int i = 0; i < 4; ++i)
#pragma unroll
      for (int j = 0; j < 4; ++j) {
        f16x4 v = {(f16)acc[i][j][0], (f16)acc[i][j][1],
                   (f16)acc[i][j][2], (f16)acc[i][j][3]};
        *(f16x4*)&T[(wn + j * 16 + frow) * TS + wm + i * 16 + q * 4] = v;
      }
    __syncthreads();
    f16* C = (f16*)Cbase;
    const int b = m0 >> 11, sl = m0 & 2047;
    const int row = tid >> 1, seg = (tid & 1) * 64;
#pragma unroll
    for (int k = 0; k < 8; ++k) {
      f16x8 v = *(const f16x8*)&T[row * TS + seg + k * 8];
      *(f16x8*)&C[(long)b * QB + (long)(n0 + row) * SEQ + sl + seg + k * 8] = v;
    }
  }
}

// ---------------- 256x256 8-phase NT GEMM (R2-measured core) ----------------
// MODE 1: f16 out = exp(acc); rowsum partials -> Rsum[z][32][2048].
// MODE 2: fp32 out = acc * (1/rowsum) from Rsum partials.

#define STG_A(B_, S_, KK_) do { \
    f16* d_ = smA + ((B_) * 2 + (S_)) * 8192 + (tid << 3); \
    const f16* s_ = gA + (KK_) + (S_) * 32; \
    async_cp16(s_, d_); async_cp16(s_ + rK, d_ + 4096); } while (0)
#define STG_B(B_, S_, KK_) do { \
    f16* d_ = smB + ((B_) * 2 + (S_)) * 8192 + (tid << 3); \
    const f16* s_ = gB + (KK_) + (S_) * 32; \
    async_cp16(s_, d_); async_cp16(s_ + rK, d_ + 4096); } while (0)
#define VMW(n_) asm volatile("s_waitcnt vmcnt(" #n_ ")" ::: "memory")
#define NOW ((void)0)

#define MFMA4(MH_, I_, AF_) do { \
    _Pragma("unroll") \
    for (int j = 0; j < 4; ++j) \
      acc[(MH_) * 4 + (I_)][j] = \
        __builtin_amdgcn_mfma_f32_16x16x32_f16(bf[j], AF_, acc[(MH_) * 4 + (I_)][j], 0, 0, 0); \
  } while (0)

#define PHASE(MH_, S_, STG_, W_) do { \
    const f16* Ar_ = smA + (buf * 2 + (S_)) * 8192 + aoff + (MH_) * 2048; \
    f16x8 a0_ = *(const f16x8*)(Ar_); \
    f16x8 a1_ = *(const f16x8*)(Ar_ + 512); \
    f16x8 a2_ = *(const f16x8*)(Ar_ + 1024); \
    f16x8 a3_ = *(const f16x8*)(Ar_ + 1536); \
    if ((MH_) == 0) { \
      const f16* Br_ = smB + (buf * 2 + (S_)) * 8192 + boff; \
      bf[0] = *(const f16x8*)(Br_); \
      bf[1] = *(const f16x8*)(Br_ + 512); \
      bf[2] = *(const f16x8*)(Br_ + 1024); \
      bf[3] = *(const f16x8*)(Br_ + 1536); \
    } \
    STG_; \
    __builtin_amdgcn_s_barrier(); \
    asm volatile("s_waitcnt lgkmcnt(0)" ::: "memory"); \
    __builtin_amdgcn_sched_barrier(0); \
    __builtin_amdgcn_s_setprio(1); \
    MFMA4(MH_, 0, a0_); MFMA4(MH_, 1, a1_); MFMA4(MH_, 2, a2_); MFMA4(MH_, 3, a3_); \
    __builtin_amdgcn_s_setprio(0); \
    W_; \
    __builtin_amdgcn_s_barrier(); \
    __builtin_amdgcn_sched_barrier(0); \
  } while (0)

template <int MODE>
__global__ __launch_bounds__(512, 2)
void gemm256(const f16* __restrict__ Abase, long sAz,
             const f16* __restrict__ Bbase, long sBz,
             void* __restrict__ Cbase, long sCz,
             float* __restrict__ Rsum,
             int N, int K)
{
  __shared__ __align__(16) char smem[131072];   // exactly 128 KiB; epilogue aliases
  f16* smA = (f16*)smem;                        // 4 regions [256][32] halfs
  f16* smB = smA + 32768;

  const int tid  = threadIdx.x;
  const int z    = blockIdx.z;
  const int m0   = blockIdx.x * 256;
  const int n0   = blockIdx.y * 256;
  const int wave = tid >> 6;
  const int lane = tid & 63;
  const int wr   = wave >> 2;         // 0..1  (M half)
  const int wc   = wave & 3;          // 0..3  (N quarter)

  const f16* A = Abase + (long)z * sAz;
  const f16* B = Bbase + (long)z * sBz;

  const int r0 = tid >> 2;
  const int gc = ((tid & 3) ^ ((tid >> 3) & 3)) * 8;
  const f16* gA = A + (long)(m0 + r0) * K + gc;
  const f16* gB = B + (long)(n0 + r0) * K + gc;
  const long rK = (long)128 * K;

  const int frow = lane & 15;
  const int q    = lane >> 4;
  const int cq   = (q ^ ((frow >> 1) & 3)) * 8;
  const int aoff = wr * 4096 + frow * 32 + cq;
  const int boff = wc * 2048 + frow * 32 + cq;

  f32x4 acc[8][4] = {};
  f16x8 bf[4];
  int buf = 0;
  const int NT = K >> 6;

  STG_A(0, 0, 0);  STG_B(0, 0, 0);
  STG_A(0, 1, 0);  STG_B(0, 1, 0);
  STG_A(1, 0, 64); STG_B(1, 0, 64);
  VMW(8);
  __builtin_amdgcn_s_barrier();
  __builtin_amdgcn_sched_barrier(0);

  for (int t = 0; t + 2 < NT; ++t) {
    const int k1 = (t + 1) << 6, k2 = (t + 2) << 6;
    const int bn = buf ^ 1;
    PHASE(0, 0, STG_A(bn, 1, k1), NOW);
    PHASE(1, 0, STG_B(bn, 1, k1), VMW(8));
    PHASE(0, 1, STG_A(buf, 0, k2), NOW);
    PHASE(1, 1, STG_B(buf, 0, k2), VMW(8));
    buf = bn;
  }
  {
    const int kl = (NT - 1) << 6;
    const int bn = buf ^ 1;
    STG_A(bn, 1, kl); STG_B(bn, 1, kl);
    VMW(4);
    PHASE(0, 0, NOW, NOW);
    PHASE(1, 0, NOW, NOW);
    PHASE(0, 1, NOW, NOW);
    PHASE(1, 1, NOW, VMW(0));
    buf = bn;
    PHASE(0, 0, NOW, NOW);
    PHASE(1, 0, NOW, NOW);
    PHASE(0, 1, NOW, NOW);
    PHASE(1, 1, NOW, NOW);
  }

  const int TS = 272;
  // output mapping: m = wr*128 + ii*16 + frow ; n = wc*64 + j*16 + q*4 + r

  if constexpr (MODE == 1) {
    f16* T = (f16*)smem;   // [128][TS]
    f16* C = (f16*)Cbase + (long)z * sCz;
    float rs[8] = {};
#pragma unroll
    for (int p = 0; p < 2; ++p) {
      if (wr == p) {
#pragma unroll
        for (int ii = 0; ii < 8; ++ii)
#pragma unroll
          for (int j = 0; j < 4; ++j) {
            f16x4 v;
#pragma unroll
            for (int r = 0; r < 4; ++r) {
              float xv = __expf(acc[ii][j][r]);
              v[r] = (f16)xv;
              rs[ii] += (float)v[r];   // sum of f16-rounded values
            }
            *(f16x4*)&T[(ii * 16 + frow) * TS + wc * 64 + j * 16 + q * 4] = v;
          }
      }
      __syncthreads();
      const int row = tid >> 2;
#pragma unroll
      for (int k = 0; k < 8; ++k) {
        const int ch = (tid & 3) + 4 * k;
        f16x8 v = *(const f16x8*)&T[row * TS + ch * 8];
        *(f16x8*)&C[(long)(m0 + p * 128 + row) * N + n0 + ch * 8] = v;
      }
      if (p == 0) __syncthreads();
    }
#pragma unroll
    for (int ii = 0; ii < 8; ++ii) {
      rs[ii] += __shfl_xor(rs[ii], 16);
      rs[ii] += __shfl_xor(rs[ii], 32);
    }
    if (lane < 16) {
      float* rp = Rsum + ((long)z * 32 + blockIdx.y * 4 + wc) * SEQ + m0 + wr * 128;
#pragma unroll
      for (int ii = 0; ii < 8; ++ii) rp[ii * 16 + frow] = rs[ii];
    }
  }

  if constexpr (MODE == 2) {   // fp32 out, normalized; 4 passes of 64 rows
    float* sinv = (float*)(smem + 102400);   // aliased, disjoint from Tf
    if (tid < 256) {
      const float* rp = Rsum + (long)z * 32 * SEQ + m0 + tid;
      float s = 0.f;
#pragma unroll
      for (int k = 0; k < 32; ++k) s += rp[k * SEQ];
      sinv[tid] = 1.0f / s;
    }
    __syncthreads();
    float inv[8];
#pragma unroll
    for (int ii = 0; ii < 8; ++ii) inv[ii] = sinv[wr * 128 + ii * 16 + frow];
    float* Tf = (float*)smem;  // [64][FS] fp32
    const int FS = 264;
    float* C = (float*)Cbase + (long)z * sCz;
#pragma unroll
    for (int p = 0; p < 4; ++p) {
      if (wr == (p >> 1)) {
        const int ib = (p & 1) * 4;
#pragma unroll
        for (int i2 = 0; i2 < 4; ++i2)
#pragma unroll
          for (int j = 0; j < 4; ++j) {
            f32x4 v = acc[ib + i2][j] * inv[ib + i2];
            *(f32x4*)&Tf[(i2 * 16 + frow) * FS + wc * 64 + j * 16 + q * 4] = v;
          }
      }
      __syncthreads();
      const int row = tid >> 3;
#pragma unroll
      for (int k = 0; k < 8; ++k) {
        const int ch = (tid & 7) + 8 * k;
        f32x4 v = *(const f32x4*)&Tf[row * FS + ch * 4];
        *(f32x4*)&C[(long)(m0 + p * 64 + row) * N + n0 + ch * 4] = v;
      }
      if (p < 3) __syncthreads();
    }
  }
}

extern "C" void kernel_launch(void* const* d_in, const int* in_sizes, int n_in,
                              void* d_out, int out_size, void* d_ws, size_t ws_size,
                              hipStream_t stream) {
  const float* x  = (const float*)d_in[0];
  const float* Wq = (const float*)d_in[1];
  const float* Wk = (const float*)d_in[2];
  const float* Wv = (const float*)d_in[3];

  f16* ws    = (f16*)d_ws;
  f16* x16   = ws;                  // XN
  f16* Wv16  = x16 + XN;            // WN
  f16* WqT16 = Wv16 + WN;           // WN
  f16* WkT16 = WqT16 + WN;          // WN
  f16* G2    = WkT16 + WN;          // WN   G2[e][d] = sum_k Wk[k][e]Wq[k][d] * scale
  f16* T16   = G2 + WN;             // XN   T~ = x @ G2^T
  f16* Vt16  = T16 + XN;            // XN   [b][d][s]
  f16* S16   = Vt16 + XN;           // NBAT*SB (exp scores, unnormalized)
  float* rsumP = (float*)(S16 + (long)NBAT * SB);   // [8][32][2048] partials

  // D1: cvt(x,Wv) + transpose(Wq,Wk), fused
  prep<<<CVTB + 1152, 256, 0, stream>>>(x, Wv, Wq, Wk, x16, Wv16, WqT16, WkT16);
  // D2: G2 = NT(WkT, WqT) * 1/sqrt(768)  (768x768x768)
  gemm128<0, true><<<dim3(6, 6, 1), 256, 0, stream>>>(
      WkT16, 0L, WqT16, 0L, (void*)G2, 0L, DIM, DIM, 0.03608439182435161f);
  // D3: T~ = NT(x16, G2)  (16384x768x768)
  gemm128<0, true><<<dim3(MTOT / BM, DIM / BN, 1), 256, 0, stream>>>(
      x16, 0L, G2, 0L, (void*)T16, 0L, DIM, DIM, 1.0f);
  // D4: Vt = (x @ Wv^T)^T per batch  (16384x768x768, transposed out)
  gemm128<3, false><<<dim3(MTOT / BM, DIM / BN, 1), 256, 0, stream>>>(
      x16, 0L, Wv16, 0L, (void*)Vt16, 0L, DIM, DIM, 1.0f);
  // D5: P' = exp(T~ x^T) per batch + rowsum partials  (2048x2048x768 x8)
  gemm256<1><<<dim3(SEQ / 256, SEQ / 256, NBAT), 512, 0, stream>>>(
      T16, QB, x16, QB, (void*)S16, SB, rsumP, SEQ, DIM);
  // D6: H = (P' @ Vt^T) / rowsum, fp32  (2048x768x2048 x8)
  gemm256<2><<<dim3(SEQ / 256, DIM / 256, NBAT), 512, 0, stream>>>(
      S16, SB, Vt16, QB, d_out, QB, rsumP, DIM, SEQ);
}